// Round 17
// baseline (89.788 us; speedup 1.0000x reference)
//
#include <hip/hip_runtime.h>
#include <hip/hip_bf16.h>
#include <stdint.h>

#define KP    416        // padded rank (396->416) and padded wemb (400->416)
#define RANKD 396
#define WEMB  400
#define TEMB  20
#define TAGS  25
#define BATCH 16
#define LSEQ  128
#define MROWS 126        // L-2
#define NM    2016       // 16*126
#define NMP   2048
#define ABC   15625
#define ABCP  15872      // 31*512
#define SCALE 0.050251890762960605f   // 1/sqrt(396)

typedef __attribute__((ext_vector_type(8))) short short8;
typedef __attribute__((ext_vector_type(4))) float f32x4;

// workspace layout (bytes)
#define OFF_T01  0                         // 2048*416*2      = 1,703,936
#define OFF_T02  1703936                   // 15872*416*2     = 13,205,504
#define OFF_WORD 14909440                  // 16*128*416*2    = 1,703,936
#define OFF_WT   16613376                  // 3*416*416*2     = 1,038,336
#define OFF_G    17651712                  // 3*25*416*4      = 124,800

#define GLOAD_LDS16(gp, lp) \
  __builtin_amdgcn_global_load_lds((const __attribute__((address_space(1))) uint32_t*)(gp), \
                                   (__attribute__((address_space(3))) uint32_t*)(lp), 16, 0, 0)

__device__ __forceinline__ uint16_t f2bf(float f) {
    union { float f; uint32_t u; } v; v.f = f;
    uint32_t u = v.u;
    return (uint16_t)((u + 0x7FFFu + ((u >> 16) & 1u)) >> 16);  // RNE
}

// ---- prep (r16 version): J1 word->bf16 vectorized x8 | J2 W->Wt LDS-tiled
#define J1_BLK 416    // 2048 rows x 52 chunks of 8 / 256
#define J2_BLK 147    // 3 matrices x 7x7 tiles of 64x64
#define J3_BLK 122    // ceil(3*25*416/256)
__global__ __launch_bounds__(256) void k_prep(const float* __restrict__ word,
                       const float* __restrict__ W1, const float* __restrict__ W2,
                       const float* __restrict__ W3, const float* __restrict__ tag,
                       const float* __restrict__ T1, const float* __restrict__ T2,
                       const float* __restrict__ T3,
                       uint16_t* __restrict__ wordb, uint16_t* __restrict__ wt,
                       float* __restrict__ g) {
    int bx = blockIdx.x;
    int tid = threadIdx.x;
    if (bx < J1_BLK) {
        int idx = bx * 256 + tid;
        int row = idx / 52, ch = idx % 52;
        int e0 = ch * 8;
        short8 o;
        if (e0 < WEMB) {
            const float4* p = (const float4*)(word + (size_t)row * WEMB + e0);
            float4 a = p[0], b = p[1];
            o[0] = (short)f2bf(a.x); o[1] = (short)f2bf(a.y);
            o[2] = (short)f2bf(a.z); o[3] = (short)f2bf(a.w);
            o[4] = (short)f2bf(b.x); o[5] = (short)f2bf(b.y);
            o[6] = (short)f2bf(b.z); o[7] = (short)f2bf(b.w);
        } else {
            for (int t = 0; t < 8; ++t) o[t] = 0;
        }
        *(short8*)(wordb + (size_t)row * KP + e0) = o;
    } else if (bx < J1_BLK + J2_BLK) {
        __shared__ float lt[64 * 68];
        int bx2 = bx - J1_BLK;
        int j = bx2 / 49, t2 = bx2 % 49;
        int e0 = (t2 / 7) * 64, k0 = (t2 % 7) * 64;
        const float* W = (j == 0) ? W1 : (j == 1) ? W2 : W3;
        int r = tid >> 4, c4 = tid & 15;
        int kc = k0 + c4 * 4;
#pragma unroll
        for (int j4 = 0; j4 < 4; ++j4) {
            int er = e0 + j4 * 16 + r;
            float4 v = {0.f, 0.f, 0.f, 0.f};
            if (er < WEMB) {
                if (kc + 3 < RANKD) {
                    v = *(const float4*)(W + (size_t)er * RANKD + kc);
                } else {
                    if (kc     < RANKD) v.x = W[(size_t)er * RANKD + kc];
                    if (kc + 1 < RANKD) v.y = W[(size_t)er * RANKD + kc + 1];
                    if (kc + 2 < RANKD) v.z = W[(size_t)er * RANKD + kc + 2];
                    if (kc + 3 < RANKD) v.w = W[(size_t)er * RANKD + kc + 3];
                }
            }
            *(float4*)&lt[(j4 * 16 + r) * 68 + c4 * 4] = v;
        }
        __syncthreads();
        int kk = tid >> 2, ee0 = (tid & 3) * 16;
        if (k0 + kk < KP && e0 + ee0 < KP) {
#pragma unroll
            for (int h = 0; h < 2; ++h) {
                short8 o;
#pragma unroll
                for (int i = 0; i < 8; ++i)
                    o[i] = (short)f2bf(lt[(ee0 + h * 8 + i) * 68 + kk]);
                *(short8*)(wt + (size_t)j * KP * KP + (size_t)(k0 + kk) * KP + e0 + ee0 + h * 8) = o;
            }
        }
    } else {
        int idx = (bx - J1_BLK - J2_BLK) * 256 + tid;
        if (idx >= 3 * TAGS * KP) return;
        int j = idx / (TAGS * KP);
        int rem = idx % (TAGS * KP);
        int a = rem / KP, k = rem % KP;
        const float* T = (j == 0) ? T1 : (j == 1) ? T2 : T3;
        float s = 0.f;
        if (k < RANKD) {
            for (int e = 0; e < TEMB; ++e) s += tag[a * TEMB + e] * T[e * RANKD + k];
        }
        g[idx] = s;
    }
}

// ---- mid (r16 version): t01 build blocks [0,896) | t02 build blocks [896,...)
#define T01_BLK 896    // 128 nm-tiles * 7 k-groups
#define T02_BLK 3224   // 15872*52/256
__global__ __launch_bounds__(256) void k_mid(const uint16_t* __restrict__ word,
                                             const uint16_t* __restrict__ wt,
                                             const float* __restrict__ g,
                                             uint16_t* __restrict__ t01,
                                             uint16_t* __restrict__ t02) {
    int bx = blockIdx.x;
    if (bx < T01_BLK) {
        int wid = threadIdx.x >> 6, lane = threadIdx.x & 63;
        int nmtile = bx & 127;
        int ktile = (bx >> 7) * 4 + wid;
        if (ktile >= KP / 16) return;
        int col_l = lane & 15, kblk = lane >> 4;
        int colk = ktile * 16 + col_l;
        f32x4 acc1 = {0.f, 0.f, 0.f, 0.f}, acc2 = acc1, acc3 = acc1;
        if (nmtile < NM / 16) {
            int nm_a = nmtile * 16 + col_l;
            int n = nm_a / MROWS, m = nm_a % MROWS;
            const uint16_t* arow = word + (size_t)(n * LSEQ + m) * KP;
            const uint16_t* b1 = wt + (size_t)colk * KP;
            const uint16_t* b2 = wt + (size_t)KP * KP + (size_t)colk * KP;
            const uint16_t* b3 = wt + (size_t)2 * KP * KP + (size_t)colk * KP;
            for (int e0 = 0; e0 < KP; e0 += 32) {
                int eo = e0 + kblk * 8;
                short8 a0 = *(const short8*)(arow + eo);
                short8 a1 = *(const short8*)(arow + KP + eo);
                short8 a2 = *(const short8*)(arow + 2 * KP + eo);
                short8 v1 = *(const short8*)(b1 + eo);
                short8 v2 = *(const short8*)(b2 + eo);
                short8 v3 = *(const short8*)(b3 + eo);
                acc1 = __builtin_amdgcn_mfma_f32_16x16x32_bf16(a0, v1, acc1, 0, 0, 0);
                acc2 = __builtin_amdgcn_mfma_f32_16x16x32_bf16(a1, v2, acc2, 0, 0, 0);
                acc3 = __builtin_amdgcn_mfma_f32_16x16x32_bf16(a2, v3, acc3, 0, 0, 0);
            }
        }
        for (int r = 0; r < 4; ++r) {
            int row = nmtile * 16 + kblk * 4 + r;
            float v = acc1[r] * acc2[r] * acc3[r] * SCALE;
            t01[(size_t)row * KP + colk] = f2bf(v);
        }
    } else {
        int idx = (bx - T01_BLK) * 256 + threadIdx.x;
        int abc = idx / (KP / 8), kc = idx % (KP / 8);
        int k0 = kc * 8;
        short8 o;
        if (abc < ABC) {
            int a = abc / 625, rem = abc % 625, b = rem / 25, c = rem % 25;
            const float4* ga = (const float4*)(g + (size_t)a * KP + k0);
            const float4* gb = (const float4*)(g + (size_t)TAGS * KP + (size_t)b * KP + k0);
            const float4* gc = (const float4*)(g + (size_t)2 * TAGS * KP + (size_t)c * KP + k0);
            float4 a0 = ga[0], a1 = ga[1];
            float4 b0 = gb[0], b1 = gb[1];
            float4 c0 = gc[0], c1 = gc[1];
            o[0] = (short)f2bf(a0.x * b0.x * c0.x);
            o[1] = (short)f2bf(a0.y * b0.y * c0.y);
            o[2] = (short)f2bf(a0.z * b0.z * c0.z);
            o[3] = (short)f2bf(a0.w * b0.w * c0.w);
            o[4] = (short)f2bf(a1.x * b1.x * c1.x);
            o[5] = (short)f2bf(a1.y * b1.y * c1.y);
            o[6] = (short)f2bf(a1.z * b1.z * c1.z);
            o[7] = (short)f2bf(a1.w * b1.w * c1.w);
        } else {
            for (int t = 0; t < 8; ++t) o[t] = 0;
        }
        *(short8*)(t02 + (size_t)abc * KP + k0) = o;
    }
}

// ---- final: score[2016][15625] = t01 @ t02^T
// Barrier-free K-loop, 64(M)x512(N) tile, 8 WAVES (wave = 64x64, same body
// as r9). One 53 KB A-panel feeds 8 waves -> 992 blocks (B L2 traffic
// halved), 3 blocks/CU x 8 waves = 24 waves/CU (2x TLP). nt f32x4 stores.
__global__ __launch_bounds__(512) void k_final(const uint16_t* __restrict__ t01,
                                               const uint16_t* __restrict__ t02,
                                               float* __restrict__ out) {
    __shared__ __align__(16) uint16_t ldsA[64 * KP];   // 53,248 B
    float* lbuf = (float*)ldsA;                        // epilogue reuse [16][520]

    const int tid = threadIdx.x;
    const int wid = tid >> 6, lane = tid & 63;
    const int col_l = lane & 15, kblk = lane >> 4;

    // 992 blocks = 8 XCD-chunks x 124; M-fastest within chunk (B-panel L2 reuse)
    const int gidx = (blockIdx.x & 7) * 124 + (blockIdx.x >> 3);
    const int mb = gidx & 31, nb = gidx >> 5;          // 32 M x 31 N
    const int brow = mb * 64, bcol = nb * 512;
    const int wcol = wid * 64;

    // ---- stage A panel once: LDS [ks 0..51][row 0..63][8] ----
    {
        const int rS = tid & 63, ksS = tid >> 6;       // 8 ks-planes per pass
        const uint16_t* gAsrc = t01 + (size_t)(brow + rS) * KP + ksS * 8;
        char* ldst = (char*)ldsA + wid * 1024;
#pragma unroll
        for (int t = 0; t < 6; ++t)
            GLOAD_LDS16(gAsrc + t * 64, ldst + t * 8192);   // ks 0..47
        if (wid < 4)                                        // ks 48..51
            GLOAD_LDS16(gAsrc + 6 * 64, ldst + 6 * 8192);
    }

    // B fragment base pointers (per n-tile); K offsets are immediates.
    const uint16_t* gBn[4];
#pragma unroll
    for (int n = 0; n < 4; ++n)
        gBn[n] = t02 + (size_t)(bcol + wcol + n * 16 + col_l) * KP + kblk * 8;

    f32x4 acc[4][4];
#pragma unroll
    for (int m = 0; m < 4; ++m)
#pragma unroll
        for (int n = 0; n < 4; ++n)
            acc[m][n] = (f32x4){0.f, 0.f, 0.f, 0.f};

    short8 bP[4];
#pragma unroll
    for (int n = 0; n < 4; ++n) bP[n] = *(const short8*)(gBn[n]);

    __syncthreads();   // A panel resident (the ONLY pre-epilogue barrier)

    const int NT = KP / 32;   // 13
#pragma unroll
    for (int kt = 0; kt < NT; ++kt) {
        short8 bF[4];
#pragma unroll
        for (int n = 0; n < 4; ++n) bF[n] = bP[n];
        if (kt + 1 < NT) {
#pragma unroll
            for (int n = 0; n < 4; ++n)
                bP[n] = *(const short8*)(gBn[n] + (kt + 1) * 32);
        }
        short8 aF[4];
#pragma unroll
        for (int m = 0; m < 4; ++m)
            aF[m] = *(const short8*)(ldsA + (kt * 4 + kblk) * 512 + (m * 16 + col_l) * 8);
#pragma unroll
        for (int m = 0; m < 4; ++m)
#pragma unroll
            for (int n = 0; n < 4; ++n)
                acc[m][n] = __builtin_amdgcn_mfma_f32_16x16x32_bf16(aF[m], bF[n], acc[m][n], 0, 0, 0);
    }

    // ---- epilogue: 4 chunks of 16 rows; LDS transpose -> nt f32x4 stores ----
    __syncthreads();   // all waves done reading ldsA
#pragma unroll
    for (int ch = 0; ch < 4; ++ch) {
        // scatter acc[ch] (rows 16ch..16ch+15, all 512 cols) -> lbuf[16][520]
#pragma unroll
        for (int n = 0; n < 4; ++n)
#pragma unroll
            for (int r = 0; r < 4; ++r)
                lbuf[(kblk * 4 + r) * 520 + wcol + n * 16 + col_l] = acc[ch][n][r];
        __syncthreads();
        // gather: 4 passes x 512 threads; 1 KB contiguous per wave-instr
#pragma unroll
        for (int p = 0; p < 4; ++p) {
            int idx = p * 512 + tid;
            int rl = idx >> 7, cv = idx & 127;
            int grow = brow + ch * 16 + rl;
            int gcol = bcol + cv * 4;
            if (grow < NM) {
                f32x4 v = *(const f32x4*)&lbuf[rl * 520 + cv * 4];
                float* po = out + (size_t)grow * ABC + gcol;
                if (gcol + 3 < ABC) {
                    __builtin_nontemporal_store(v, (f32x4*)po);
                } else {
                    if (gcol     < ABC) po[0] = v[0];
                    if (gcol + 1 < ABC) po[1] = v[1];
                    if (gcol + 2 < ABC) po[2] = v[2];
                }
            }
        }
        if (ch < 3) __syncthreads();
    }
}

extern "C" void kernel_launch(void* const* d_in, const int* in_sizes, int n_in,
                              void* d_out, int out_size, void* d_ws, size_t ws_size,
                              hipStream_t stream) {
    const float* word = (const float*)d_in[0];
    const float* tag  = (const float*)d_in[1];
    const float* W1   = (const float*)d_in[2];
    const float* W2   = (const float*)d_in[3];
    const float* W3   = (const float*)d_in[4];
    const float* T1   = (const float*)d_in[5];
    const float* T2   = (const float*)d_in[6];
    const float* T3   = (const float*)d_in[7];
    float* out = (float*)d_out;
    char* ws = (char*)d_ws;

    uint16_t* t01   = (uint16_t*)(ws + OFF_T01);
    uint16_t* t02   = (uint16_t*)(ws + OFF_T02);
    uint16_t* wordb = (uint16_t*)(ws + OFF_WORD);
    uint16_t* wt    = (uint16_t*)(ws + OFF_WT);
    float*    g     = (float*)(ws + OFF_G);

    k_prep<<<J1_BLK + J2_BLK + J3_BLK, 256, 0, stream>>>(word, W1, W2, W3, tag,
                                                         T1, T2, T3, wordb, wt, g);
    k_mid<<<T01_BLK + T02_BLK, 256, 0, stream>>>(wordb, wt, g, t01, t02);
    k_final<<<32 * 31, 512, 0, stream>>>(t01, t02, out);
}

// Round 18
// 82.081 us; speedup vs baseline: 1.0939x; 1.0939x over previous
//
#include <hip/hip_runtime.h>
#include <hip/hip_bf16.h>
#include <stdint.h>

#define KP    416        // padded rank (396->416) and padded wemb (400->416)
#define RANKD 396
#define WEMB  400
#define TEMB  20
#define TAGS  25
#define BATCH 16
#define LSEQ  128
#define MROWS 126        // L-2
#define NM    2016       // 16*126
#define NMP   2048
#define ABC   15625
#define ABCP  15872      // 62*256
#define SCALE 0.050251890762960605f   // 1/sqrt(396)

typedef __attribute__((ext_vector_type(8))) short short8;
typedef __attribute__((ext_vector_type(4))) float f32x4;

// workspace layout (bytes)
#define OFF_T01  0                         // 2048*416*2      = 1,703,936
#define OFF_T02  1703936                   // 15872*416*2     = 13,205,504
#define OFF_WORD 14909440                  // 16*128*416*2    = 1,703,936
#define OFF_WT   16613376                  // 3*416*416*2     = 1,038,336
#define OFF_G    17651712                  // 3*25*416*4      = 124,800

#define GLOAD_LDS16(gp, lp) \
  __builtin_amdgcn_global_load_lds((const __attribute__((address_space(1))) uint32_t*)(gp), \
                                   (__attribute__((address_space(3))) uint32_t*)(lp), 16, 0, 0)

__device__ __forceinline__ uint16_t f2bf(float f) {
    union { float f; uint32_t u; } v; v.f = f;
    uint32_t u = v.u;
    return (uint16_t)((u + 0x7FFFu + ((u >> 16) & 1u)) >> 16);  // RNE
}

// ---- prep: J1 word->bf16 vectorized x8 | J2 W->Wt LDS-tiled coalesced
//      transpose | J3 g. 685 blocks.
#define J1_BLK 416    // 2048 rows x 52 chunks of 8 / 256
#define J2_BLK 147    // 3 matrices x 7x7 tiles of 64x64
#define J3_BLK 122    // ceil(3*25*416/256)
__global__ __launch_bounds__(256) void k_prep(const float* __restrict__ word,
                       const float* __restrict__ W1, const float* __restrict__ W2,
                       const float* __restrict__ W3, const float* __restrict__ tag,
                       const float* __restrict__ T1, const float* __restrict__ T2,
                       const float* __restrict__ T3,
                       uint16_t* __restrict__ wordb, uint16_t* __restrict__ wt,
                       float* __restrict__ g) {
    int bx = blockIdx.x;
    int tid = threadIdx.x;
    if (bx < J1_BLK) {
        int idx = bx * 256 + tid;
        int row = idx / 52, ch = idx % 52;
        int e0 = ch * 8;
        short8 o;
        if (e0 < WEMB) {
            const float4* p = (const float4*)(word + (size_t)row * WEMB + e0);
            float4 a = p[0], b = p[1];
            o[0] = (short)f2bf(a.x); o[1] = (short)f2bf(a.y);
            o[2] = (short)f2bf(a.z); o[3] = (short)f2bf(a.w);
            o[4] = (short)f2bf(b.x); o[5] = (short)f2bf(b.y);
            o[6] = (short)f2bf(b.z); o[7] = (short)f2bf(b.w);
        } else {
            for (int t = 0; t < 8; ++t) o[t] = 0;
        }
        *(short8*)(wordb + (size_t)row * KP + e0) = o;
    } else if (bx < J1_BLK + J2_BLK) {
        __shared__ float lt[64 * 68];
        int bx2 = bx - J1_BLK;
        int j = bx2 / 49, t2 = bx2 % 49;
        int e0 = (t2 / 7) * 64, k0 = (t2 % 7) * 64;
        const float* W = (j == 0) ? W1 : (j == 1) ? W2 : W3;
        int r = tid >> 4, c4 = tid & 15;
        int kc = k0 + c4 * 4;
#pragma unroll
        for (int j4 = 0; j4 < 4; ++j4) {
            int er = e0 + j4 * 16 + r;
            float4 v = {0.f, 0.f, 0.f, 0.f};
            if (er < WEMB) {
                if (kc + 3 < RANKD) {
                    v = *(const float4*)(W + (size_t)er * RANKD + kc);
                } else {
                    if (kc     < RANKD) v.x = W[(size_t)er * RANKD + kc];
                    if (kc + 1 < RANKD) v.y = W[(size_t)er * RANKD + kc + 1];
                    if (kc + 2 < RANKD) v.z = W[(size_t)er * RANKD + kc + 2];
                    if (kc + 3 < RANKD) v.w = W[(size_t)er * RANKD + kc + 3];
                }
            }
            *(float4*)&lt[(j4 * 16 + r) * 68 + c4 * 4] = v;
        }
        __syncthreads();
        int kk = tid >> 2, ee0 = (tid & 3) * 16;
        if (k0 + kk < KP && e0 + ee0 < KP) {
#pragma unroll
            for (int h = 0; h < 2; ++h) {
                short8 o;
#pragma unroll
                for (int i = 0; i < 8; ++i)
                    o[i] = (short)f2bf(lt[(ee0 + h * 8 + i) * 68 + kk]);
                *(short8*)(wt + (size_t)j * KP * KP + (size_t)(k0 + kk) * KP + e0 + ee0 + h * 8) = o;
            }
        }
    } else {
        int idx = (bx - J1_BLK - J2_BLK) * 256 + tid;
        if (idx >= 3 * TAGS * KP) return;
        int j = idx / (TAGS * KP);
        int rem = idx % (TAGS * KP);
        int a = rem / KP, k = rem % KP;
        const float* T = (j == 0) ? T1 : (j == 1) ? T2 : T3;
        float s = 0.f;
        if (k < RANKD) {
            for (int e = 0; e < TEMB; ++e) s += tag[a * TEMB + e] * T[e * RANKD + k];
        }
        g[idx] = s;
    }
}

// ---- mid: t01 build (MFMA) blocks [0,896) | t02 build blocks [896,...)
#define T01_BLK 896    // 128 nm-tiles * 7 k-groups
#define T02_BLK 3224   // 15872*52/256
__global__ __launch_bounds__(256) void k_mid(const uint16_t* __restrict__ word,
                                             const uint16_t* __restrict__ wt,
                                             const float* __restrict__ g,
                                             uint16_t* __restrict__ t01,
                                             uint16_t* __restrict__ t02) {
    int bx = blockIdx.x;
    if (bx < T01_BLK) {
        int wid = threadIdx.x >> 6, lane = threadIdx.x & 63;
        int nmtile = bx & 127;
        int ktile = (bx >> 7) * 4 + wid;
        if (ktile >= KP / 16) return;
        int col_l = lane & 15, kblk = lane >> 4;
        int colk = ktile * 16 + col_l;
        f32x4 acc1 = {0.f, 0.f, 0.f, 0.f}, acc2 = acc1, acc3 = acc1;
        if (nmtile < NM / 16) {
            int nm_a = nmtile * 16 + col_l;
            int n = nm_a / MROWS, m = nm_a % MROWS;
            const uint16_t* arow = word + (size_t)(n * LSEQ + m) * KP;
            const uint16_t* b1 = wt + (size_t)colk * KP;
            const uint16_t* b2 = wt + (size_t)KP * KP + (size_t)colk * KP;
            const uint16_t* b3 = wt + (size_t)2 * KP * KP + (size_t)colk * KP;
            for (int e0 = 0; e0 < KP; e0 += 32) {
                int eo = e0 + kblk * 8;
                short8 a0 = *(const short8*)(arow + eo);
                short8 a1 = *(const short8*)(arow + KP + eo);
                short8 a2 = *(const short8*)(arow + 2 * KP + eo);
                short8 v1 = *(const short8*)(b1 + eo);
                short8 v2 = *(const short8*)(b2 + eo);
                short8 v3 = *(const short8*)(b3 + eo);
                acc1 = __builtin_amdgcn_mfma_f32_16x16x32_bf16(a0, v1, acc1, 0, 0, 0);
                acc2 = __builtin_amdgcn_mfma_f32_16x16x32_bf16(a1, v2, acc2, 0, 0, 0);
                acc3 = __builtin_amdgcn_mfma_f32_16x16x32_bf16(a2, v3, acc3, 0, 0, 0);
            }
        }
        for (int r = 0; r < 4; ++r) {
            int row = nmtile * 16 + kblk * 4 + r;
            float v = acc1[r] * acc2[r] * acc3[r] * SCALE;
            t01[(size_t)row * KP + colk] = f2bf(v);
        }
    } else {
        int idx = (bx - T01_BLK) * 256 + threadIdx.x;
        int abc = idx / (KP / 8), kc = idx % (KP / 8);
        int k0 = kc * 8;
        short8 o;
        if (abc < ABC) {
            int a = abc / 625, rem = abc % 625, b = rem / 25, c = rem % 25;
            const float4* ga = (const float4*)(g + (size_t)a * KP + k0);
            const float4* gb = (const float4*)(g + (size_t)TAGS * KP + (size_t)b * KP + k0);
            const float4* gc = (const float4*)(g + (size_t)2 * TAGS * KP + (size_t)c * KP + k0);
            float4 a0 = ga[0], a1 = ga[1];
            float4 b0 = gb[0], b1 = gb[1];
            float4 c0 = gc[0], c1 = gc[1];
            o[0] = (short)f2bf(a0.x * b0.x * c0.x);
            o[1] = (short)f2bf(a0.y * b0.y * c0.y);
            o[2] = (short)f2bf(a0.z * b0.z * c0.z);
            o[3] = (short)f2bf(a0.w * b0.w * c0.w);
            o[4] = (short)f2bf(a1.x * b1.x * c1.x);
            o[5] = (short)f2bf(a1.y * b1.y * c1.y);
            o[6] = (short)f2bf(a1.z * b1.z * c1.z);
            o[7] = (short)f2bf(a1.w * b1.w * c1.w);
        } else {
            for (int t = 0; t < 8; ++t) o[t] = 0;
        }
        *(short8*)(t02 + (size_t)abc * KP + k0) = o;
    }
}

// ---- final (r9 verbatim): score[2016][15625] = t01 @ t02^T
// Barrier-free K-loop: 64(M)x256(N) tile, 4 waves (wave = 64x64).
// A panel 64x416 staged in LDS ONCE; B streamed global->reg depth-1.
// M-fastest XCD swizzle (B-panel L2 reuse). nt f32x4 stores, 1 KB runs.
__global__ __launch_bounds__(256) void k_final(const uint16_t* __restrict__ t01,
                                               const uint16_t* __restrict__ t02,
                                               float* __restrict__ out) {
    __shared__ __align__(16) uint16_t ldsA[64 * KP];   // 53,248 B
    float* lbuf = (float*)ldsA;                        // epilogue reuse [32][260]

    const int tid = threadIdx.x;
    const int wid = tid >> 6, lane = tid & 63;
    const int col_l = lane & 15, kblk = lane >> 4;

    // 1984 blocks = 8 XCD-chunks x 248; M-fastest within chunk: 32 consecutive
    // blocks share one B-panel (208 KB, L2-resident per XCD).
    const int gidx = (blockIdx.x & 7) * 248 + (blockIdx.x >> 3);
    const int mb = gidx & 31, nb = gidx >> 5;          // 32 M x 62 N
    const int brow = mb * 64, bcol = nb * 256;
    const int wcol = wid * 64;

    // ---- stage A panel once: LDS [ks 0..51][row 0..63][8] ----
    {
        const uint16_t* gAsrc = t01 + (size_t)(brow + lane) * KP + wid * 8;
        char* ldst = (char*)ldsA + wid * 1024;
#pragma unroll
        for (int t = 0; t < 13; ++t)
            GLOAD_LDS16(gAsrc + t * 32, ldst + t * 4096);
    }

    // B fragment base pointers (per n-tile); K offsets are immediates.
    const uint16_t* gBn[4];
#pragma unroll
    for (int n = 0; n < 4; ++n)
        gBn[n] = t02 + (size_t)(bcol + wcol + n * 16 + col_l) * KP + kblk * 8;

    f32x4 acc[4][4];
#pragma unroll
    for (int m = 0; m < 4; ++m)
#pragma unroll
        for (int n = 0; n < 4; ++n)
            acc[m][n] = (f32x4){0.f, 0.f, 0.f, 0.f};

    short8 bP[4];
#pragma unroll
    for (int n = 0; n < 4; ++n) bP[n] = *(const short8*)(gBn[n]);

    __syncthreads();   // A panel resident (the ONLY pre-epilogue barrier)

    const int NT = KP / 32;   // 13
#pragma unroll
    for (int kt = 0; kt < NT; ++kt) {
        short8 bF[4];
#pragma unroll
        for (int n = 0; n < 4; ++n) bF[n] = bP[n];
        if (kt + 1 < NT) {
#pragma unroll
            for (int n = 0; n < 4; ++n)
                bP[n] = *(const short8*)(gBn[n] + (kt + 1) * 32);
        }
        short8 aF[4];
#pragma unroll
        for (int m = 0; m < 4; ++m)
            aF[m] = *(const short8*)(ldsA + (kt * 4 + kblk) * 512 + (m * 16 + col_l) * 8);
#pragma unroll
        for (int m = 0; m < 4; ++m)
#pragma unroll
            for (int n = 0; n < 4; ++n)
                acc[m][n] = __builtin_amdgcn_mfma_f32_16x16x32_bf16(aF[m], bF[n], acc[m][n], 0, 0, 0);
    }

    // ---- epilogue: LDS transpose -> coalesced non-temporal f32x4 stores ----
    __syncthreads();   // all waves done reading ldsA
#pragma unroll
    for (int ch = 0; ch < 2; ++ch) {
        // scatter rows ch*32..+31 (acc m = 2ch, 2ch+1) into lbuf[32][260]
#pragma unroll
        for (int mm = 0; mm < 2; ++mm) {
            const int m = ch * 2 + mm;
#pragma unroll
            for (int n = 0; n < 4; ++n)
#pragma unroll
                for (int r = 0; r < 4; ++r) {
                    int row_l = mm * 16 + kblk * 4 + r;      // 0..31
                    int col = wcol + n * 16 + col_l;         // 0..255
                    lbuf[row_l * 260 + col] = acc[m][n][r];
                }
        }
        __syncthreads();
        // gather: 8 iters x 4 rows; wave writes 1 KB contiguous per row
#pragma unroll
        for (int it = 0; it < 8; ++it) {
            int row_l = it * 4 + wid;
            int grow = brow + ch * 32 + row_l;
            int gcol = bcol + lane * 4;
            if (grow < NM) {
                f32x4 v = *(const f32x4*)&lbuf[row_l * 260 + lane * 4];
                float* po = out + (size_t)grow * ABC + gcol;
                if (gcol + 3 < ABC) {
                    __builtin_nontemporal_store(v, (f32x4*)po);
                } else {
                    if (gcol     < ABC) po[0] = v[0];
                    if (gcol + 1 < ABC) po[1] = v[1];
                    if (gcol + 2 < ABC) po[2] = v[2];
                }
            }
        }
        if (ch == 0) __syncthreads();
    }
}

extern "C" void kernel_launch(void* const* d_in, const int* in_sizes, int n_in,
                              void* d_out, int out_size, void* d_ws, size_t ws_size,
                              hipStream_t stream) {
    const float* word = (const float*)d_in[0];
    const float* tag  = (const float*)d_in[1];
    const float* W1   = (const float*)d_in[2];
    const float* W2   = (const float*)d_in[3];
    const float* W3   = (const float*)d_in[4];
    const float* T1   = (const float*)d_in[5];
    const float* T2   = (const float*)d_in[6];
    const float* T3   = (const float*)d_in[7];
    float* out = (float*)d_out;
    char* ws = (char*)d_ws;

    uint16_t* t01   = (uint16_t*)(ws + OFF_T01);
    uint16_t* t02   = (uint16_t*)(ws + OFF_T02);
    uint16_t* wordb = (uint16_t*)(ws + OFF_WORD);
    uint16_t* wt    = (uint16_t*)(ws + OFF_WT);
    float*    g     = (float*)(ws + OFF_G);

    k_prep<<<J1_BLK + J2_BLK + J3_BLK, 256, 0, stream>>>(word, W1, W2, W3, tag,
                                                         T1, T2, T3, wordb, wt, g);
    k_mid<<<T01_BLK + T02_BLK, 256, 0, stream>>>(wordb, wt, g, t01, t02);
    k_final<<<32 * 62, 256, 0, stream>>>(t01, t02, out);
}